// Round 1
// baseline (572.977 us; speedup 1.0000x reference)
//
#include <hip/hip_runtime.h>
#include <hip/hip_bf16.h>
#include <hip/hip_fp16.h>

#define ETA 0.15f
#define LAM 0.05f

typedef unsigned int uint32;
typedef __attribute__((ext_vector_type(8))) short short8;
typedef __attribute__((ext_vector_type(4))) float floatx4;

static const int BSZ = 32, LL = 8192, DD = 64;
static const int RTOT = BSZ * LL; // 262144 rows

// workspace layout (bytes)
static const size_t MU_BYTES = (size_t)RTOT * DD * 2;   // mu as fp16
static const size_t W1T_OFF  = MU_BYTES;                // [256][128] bf16
static const size_t W2T_OFF  = W1T_OFF + 256 * 128 * 2; // [64][256] bf16
static const size_t WQT_OFF  = W2T_OFF + 64 * 256 * 2;  // [64][64] bf16

__device__ __forceinline__ unsigned short f2bf(float f) {
    uint32 u = __builtin_bit_cast(uint32, f);
    uint32 r = (u + 0x7FFFu + ((u >> 16) & 1u)) >> 16;
    return (unsigned short)r;
}

// ---------------- prep: zero energy, transpose weights to bf16 ----------------
__global__ void prep_kernel(const float* __restrict__ W1, const float* __restrict__ W2,
                            const float* __restrict__ Wq,
                            unsigned short* __restrict__ w1t, unsigned short* __restrict__ w2t,
                            unsigned short* __restrict__ wqt, float* __restrict__ energy) {
    int tid = blockIdx.x * blockDim.x + threadIdx.x;
    int nth = gridDim.x * blockDim.x;
    for (int i = tid; i < 256 * 128; i += nth) { int n = i >> 7, k = i & 127; w1t[i] = f2bf(W1[k * 256 + n]); }
    for (int i = tid; i < 64 * 256; i += nth) { int n = i >> 8, k = i & 255; w2t[i] = f2bf(W2[k * 64 + n]); }
    for (int i = tid; i < 64 * 64;  i += nth) { int n = i >> 6, k = i & 63;  wqt[i] = f2bf(Wq[k * 64 + n]); }
    if (tid < 32) energy[tid] = 0.f;
}

// ---------------- MLP: mu = softplus(relu([A|B]@W1+b1)@W2+b2)*(1+0.5*tanh(q@Wq+bq)) ----------------
// 64 rows per block, 4 waves, each wave owns a 16-row MFMA tile.
// LDS regions (52224 B total):
//   phase1: Xs [64][136] bf16 @0 (17408), Ws [128][136] bf16 @17408 (34816)
//   phase2: Zs [64][264] bf16 @0 (33792), Qs [64][72] @33792 (9216), Wqs [64][72] @43008 (9216)
__global__ __launch_bounds__(256) void mlp_kernel(
    const float* __restrict__ A, const float* __restrict__ B, const float* __restrict__ Q,
    const float* __restrict__ b1, const float* __restrict__ b2, const float* __restrict__ bq,
    const unsigned short* __restrict__ w1t, const unsigned short* __restrict__ w2t,
    const unsigned short* __restrict__ wqt, _Float16* __restrict__ mu_out) {
    __shared__ char lds[52224];
    unsigned short* Xs  = (unsigned short*)(lds);
    unsigned short* Ws  = (unsigned short*)(lds + 17408);
    unsigned short* Zs  = (unsigned short*)(lds);
    unsigned short* Qs  = (unsigned short*)(lds + 33792);
    unsigned short* Wqs = (unsigned short*)(lds + 43008);

    const int tid = threadIdx.x;
    const int lane = tid & 63;
    const int wave = tid >> 6;
    const int q4 = lane >> 4;
    const int l16 = lane & 15;
    const int rowbase = blockIdx.x * 64;
    const int m0 = wave * 16;

    // stage X = [A|B] as bf16 pairs
    uint32* Xu = (uint32*)Xs; // row stride 68 uints
    for (int i = tid; i < 64 * 64; i += 256) {
        int r = i >> 6, j2 = i & 63;
        const float* src = (j2 < 32) ? (A + (size_t)(rowbase + r) * 64 + 2 * j2)
                                     : (B + (size_t)(rowbase + r) * 64 + 2 * (j2 - 32));
        Xu[r * 68 + j2] = (uint32)f2bf(src[0]) | ((uint32)f2bf(src[1]) << 16);
    }
    // stage W1T half 0 (cols 0..127)
    const uint32* w1u = (const uint32*)w1t; // [256][64] uints
    uint32* Wu = (uint32*)Ws;               // row stride 68 uints
    for (int i = tid; i < 128 * 64; i += 256) {
        int n = i >> 6, kp = i & 63;
        Wu[n * 68 + kp] = w1u[n * 64 + kp];
    }
    __syncthreads();

    floatx4 acc[16];
#pragma unroll
    for (int n = 0; n < 16; n++) acc[n] = (floatx4){0.f, 0.f, 0.f, 0.f};
#pragma unroll
    for (int kt = 0; kt < 4; kt++) {
        short8 a = *(const short8*)&Xs[(m0 + l16) * 136 + kt * 32 + q4 * 8];
#pragma unroll
        for (int n = 0; n < 8; n++) {
            short8 b = *(const short8*)&Ws[(n * 16 + l16) * 136 + kt * 32 + q4 * 8];
            acc[n] = __builtin_amdgcn_mfma_f32_16x16x32_bf16(a, b, acc[n], 0, 0, 0);
        }
    }
    __syncthreads();
    // stage W1T half 1 (cols 128..255)
    for (int i = tid; i < 128 * 64; i += 256) {
        int n = i >> 6, kp = i & 63;
        Wu[n * 68 + kp] = w1u[(128 + n) * 64 + kp];
    }
    __syncthreads();
#pragma unroll
    for (int kt = 0; kt < 4; kt++) {
        short8 a = *(const short8*)&Xs[(m0 + l16) * 136 + kt * 32 + q4 * 8];
#pragma unroll
        for (int n = 0; n < 8; n++) {
            short8 b = *(const short8*)&Ws[(n * 16 + l16) * 136 + kt * 32 + q4 * 8];
            acc[8 + n] = __builtin_amdgcn_mfma_f32_16x16x32_bf16(a, b, acc[8 + n], 0, 0, 0);
        }
    }
    __syncthreads(); // everyone done reading Xs/Ws; Zs overwrites them

    // Z = relu(acc + b1) -> LDS bf16 (A-operand layout for GEMM2)
#pragma unroll
    for (int n = 0; n < 16; n++) {
        int col = n * 16 + l16;
        float b1v = b1[col];
#pragma unroll
        for (int r = 0; r < 4; r++) {
            int row = m0 + q4 * 4 + r;
            float z = acc[n][r] + b1v;
            z = z > 0.f ? z : 0.f;
            Zs[row * 264 + col] = f2bf(z);
        }
    }
    // stage q tile + WqT
    uint32* Qu = (uint32*)Qs; // stride 36 uints
    for (int i = tid; i < 64 * 32; i += 256) {
        int r = i >> 5, j2 = i & 31;
        const float* src = Q + (size_t)(rowbase + r) * 64 + 2 * j2;
        Qu[r * 36 + j2] = (uint32)f2bf(src[0]) | ((uint32)f2bf(src[1]) << 16);
    }
    const uint32* wqu = (const uint32*)wqt;
    uint32* WqU = (uint32*)Wqs;
    for (int i = tid; i < 64 * 32; i += 256) {
        int n = i >> 5, kp = i & 31;
        WqU[n * 36 + kp] = wqu[n * 32 + kp];
    }
    __syncthreads();

    // GEMM2: mu_pre = Z @ W2  (W2T b-frags straight from global bf16, L1/L2-resident)
    floatx4 acc2[4], acc3[4];
#pragma unroll
    for (int n = 0; n < 4; n++) { acc2[n] = (floatx4){0.f,0.f,0.f,0.f}; acc3[n] = (floatx4){0.f,0.f,0.f,0.f}; }
#pragma unroll
    for (int kt = 0; kt < 8; kt++) {
        short8 a = *(const short8*)&Zs[(m0 + l16) * 264 + kt * 32 + q4 * 8];
#pragma unroll
        for (int n = 0; n < 4; n++) {
            short8 b = *(const short8*)&w2t[(n * 16 + l16) * 256 + kt * 32 + q4 * 8];
            acc2[n] = __builtin_amdgcn_mfma_f32_16x16x32_bf16(a, b, acc2[n], 0, 0, 0);
        }
    }
    // GEMM3: gate_pre = q @ Wq
#pragma unroll
    for (int kt = 0; kt < 2; kt++) {
        short8 a = *(const short8*)&Qs[(m0 + l16) * 72 + kt * 32 + q4 * 8];
#pragma unroll
        for (int n = 0; n < 4; n++) {
            short8 b = *(const short8*)&Wqs[(n * 16 + l16) * 72 + kt * 32 + q4 * 8];
            acc3[n] = __builtin_amdgcn_mfma_f32_16x16x32_bf16(a, b, acc3[n], 0, 0, 0);
        }
    }
    // epilogue: softplus, tanh gate, store mu as fp16
#pragma unroll
    for (int n = 0; n < 4; n++) {
        int col = n * 16 + l16;
        float b2v = b2[col], bqv = bq[col];
#pragma unroll
        for (int r = 0; r < 4; r++) {
            int row = m0 + q4 * 4 + r;
            float x = acc2[n][r] + b2v;
            float sp = (x > 15.f) ? x : log1pf(expf(x));
            float g = tanhf(acc3[n][r] + bqv);
            float mu = sp * (1.f + 0.5f * g);
            mu_out[(size_t)(rowbase + row) * 64 + col] = (_Float16)mu;
        }
    }
}

// ---------------- K=6 iterations + energy, chunked along L with halo 6 ----------------
// CL=64 interior rows, 76 rows resident (halo 6 each side). 3 fp32 LDS buffers = 57 KB.
__global__ __launch_bounds__(256) void iter_kernel(
    const float* __restrict__ A, const float* __restrict__ B, const _Float16* __restrict__ mu_ws,
    float* __restrict__ outA, float* __restrict__ outB, float* __restrict__ energy) {
    __shared__ float sA[76 * 64];
    __shared__ float sB[76 * 64];
    __shared__ float sT[76 * 64];
    const int tid = threadIdx.x;
    const int col = tid & 63;
    const int rg = tid >> 6; // wave id = row group
    const int b = blockIdx.y;
    const int s = blockIdx.x * 64;
    const size_t bbase = (size_t)b * 8192;

    float muv[19], st[19];
#pragma unroll
    for (int i = 0; i < 19; i++) {
        int r = rg + 4 * i;
        int gl = (s + r + 8192 - 6) & 8191; // circular halo
        size_t g = (bbase + gl) * 64 + col;
        sA[r * 64 + col] = A[g];
        sB[r * 64 + col] = B[g];
        muv[i] = (float)mu_ws[g];
    }
    __syncthreads();
    for (int it = 0; it < 6; it++) {
#pragma unroll
        for (int i = 0; i < 19; i++) {
            int idx = (rg + 4 * i) * 64 + col;
            float d = sA[idx] - sB[idx];
            st[i] = ETA * muv[i] * d;
            sT[idx] = sA[idx] - st[i];
        }
        __syncthreads();
#pragma unroll
        for (int i = 0; i < 19; i++) {
            int r = rg + 4 * i;
            if (r >= 1 && r <= 74) {
                int idx = r * 64 + col;
                float t0 = sT[idx];
                sA[idx] = t0 - LAM * (2.f * t0 - sT[idx - 64] - sT[idx + 64]);
            }
        }
        __syncthreads();
#pragma unroll
        for (int i = 0; i < 19; i++) {
            int idx = (rg + 4 * i) * 64 + col;
            sT[idx] = sB[idx] + st[i];
        }
        __syncthreads();
#pragma unroll
        for (int i = 0; i < 19; i++) {
            int r = rg + 4 * i;
            if (r >= 1 && r <= 74) {
                int idx = r * 64 + col;
                float t0 = sT[idx];
                sB[idx] = t0 - LAM * (2.f * t0 - sT[idx - 64] - sT[idx + 64]);
            }
        }
        __syncthreads();
    }
    // store interior + energy partial
    float e = 0.f;
#pragma unroll
    for (int i = 0; i < 19; i++) {
        int r = rg + 4 * i;
        if (r >= 6 && r < 70) {
            int idx = r * 64 + col;
            float d = sA[idx] - sB[idx];
            e += muv[i] * d * d;
            size_t g = (bbase + s + (r - 6)) * 64 + col;
            outA[g] = sA[idx];
            outB[g] = sB[idx];
        }
    }
    e *= 0.5f;
#pragma unroll
    for (int off = 32; off > 0; off >>= 1) e += __shfl_down(e, off, 64);
    __syncthreads();
    if ((tid & 63) == 0) sT[tid >> 6] = e;
    __syncthreads();
    if (tid == 0) atomicAdd(energy + b, sT[0] + sT[1] + sT[2] + sT[3]);
}

extern "C" void kernel_launch(void* const* d_in, const int* in_sizes, int n_in,
                              void* d_out, int out_size, void* d_ws, size_t ws_size,
                              hipStream_t stream) {
    const float* A  = (const float*)d_in[0];
    const float* B  = (const float*)d_in[1];
    const float* Q  = (const float*)d_in[2];
    const float* W1 = (const float*)d_in[3];
    const float* b1 = (const float*)d_in[4];
    const float* W2 = (const float*)d_in[5];
    const float* b2 = (const float*)d_in[6];
    const float* Wq = (const float*)d_in[7];
    const float* bq = (const float*)d_in[8];

    float* outA = (float*)d_out;
    float* outB = outA + (size_t)RTOT * 64;
    float* energy = outB + (size_t)RTOT * 64;

    char* ws = (char*)d_ws;
    _Float16* mu_ws = (_Float16*)ws;
    unsigned short* w1t = (unsigned short*)(ws + W1T_OFF);
    unsigned short* w2t = (unsigned short*)(ws + W2T_OFF);
    unsigned short* wqt = (unsigned short*)(ws + WQT_OFF);

    hipLaunchKernelGGL(prep_kernel, dim3(64), dim3(256), 0, stream,
                       W1, W2, Wq, w1t, w2t, wqt, energy);
    hipLaunchKernelGGL(mlp_kernel, dim3(RTOT / 64), dim3(256), 0, stream,
                       A, B, Q, b1, b2, bq, w1t, w2t, wqt, mu_ws);
    hipLaunchKernelGGL(iter_kernel, dim3(LL / 64, BSZ), dim3(256), 0, stream,
                       A, B, mu_ws, outA, outB, energy);
}

// Round 2
// 414.059 us; speedup vs baseline: 1.3838x; 1.3838x over previous
//
#include <hip/hip_runtime.h>
#include <hip/hip_bf16.h>
#include <hip/hip_fp16.h>

#define ETA 0.15f
#define LAM 0.05f

typedef unsigned int uint32;
typedef __attribute__((ext_vector_type(8))) short short8;
typedef __attribute__((ext_vector_type(4))) float floatx4;

static const int BSZ = 32, LL = 8192, DD = 64;
static const int RTOT = BSZ * LL; // 262144 rows

// workspace layout (bytes)
static const size_t MU_BYTES = (size_t)RTOT * DD * 2;   // mu as fp16
static const size_t W1T_OFF  = MU_BYTES;                // [256][128] bf16 (n-major)
static const size_t W2T_OFF  = W1T_OFF + 256 * 128 * 2; // [64][256] bf16
static const size_t WQT_OFF  = W2T_OFF + 64 * 256 * 2;  // [64][64] bf16

__device__ __forceinline__ unsigned short f2bf(float f) {
    uint32 u = __builtin_bit_cast(uint32, f);
    uint32 r = (u + 0x7FFFu + ((u >> 16) & 1u)) >> 16;
    return (unsigned short)r;
}

// fast softplus / tanh (rel err ~1e-6, far below bf16 noise)
__device__ __forceinline__ float fast_softplus(float x) {
    return fmaxf(x, 0.f) + __logf(1.f + __expf(-fabsf(x)));
}
__device__ __forceinline__ float fast_tanh(float x) {
    float t = __expf(-2.f * fabsf(x));
    float r = (1.f - t) / (1.f + t);
    return copysignf(r, x);
}

// ---------------- prep: zero energy, transpose weights to bf16 ----------------
__global__ void prep_kernel(const float* __restrict__ W1, const float* __restrict__ W2,
                            const float* __restrict__ Wq,
                            unsigned short* __restrict__ w1t, unsigned short* __restrict__ w2t,
                            unsigned short* __restrict__ wqt, float* __restrict__ energy) {
    int tid = blockIdx.x * blockDim.x + threadIdx.x;
    int nth = gridDim.x * blockDim.x;
    for (int i = tid; i < 256 * 128; i += nth) { int n = i >> 7, k = i & 127; w1t[i] = f2bf(W1[k * 256 + n]); }
    for (int i = tid; i < 64 * 256; i += nth) { int n = i >> 8, k = i & 255; w2t[i] = f2bf(W2[k * 64 + n]); }
    for (int i = tid; i < 64 * 64;  i += nth) { int n = i >> 6, k = i & 63;  wqt[i] = f2bf(Wq[k * 64 + n]); }
    if (tid < 32) energy[tid] = 0.f;
}

// ---------------- MLP: mu = softplus(relu([A|B]@W1+b1)@W2+b2)*(1+0.5*tanh(q@Wq+bq)) ----------------
// 64 rows/block, 4 waves. N-SPLIT: wave w owns output cols [w*64,w*64+64) of Z (GEMM1)
// and cols [w*16,w*16+16) of mu/gate (GEMM2/3). Weight B-frags live in REGISTERS,
// loaded straight from bf16 workspace (L2-hot). Only X/Q/Z touch LDS. 2 barriers.
__global__ __launch_bounds__(256) void mlp_kernel(
    const float* __restrict__ A, const float* __restrict__ B, const float* __restrict__ Q,
    const float* __restrict__ b1, const float* __restrict__ b2, const float* __restrict__ bq,
    const unsigned short* __restrict__ w1t, const unsigned short* __restrict__ w2t,
    const unsigned short* __restrict__ wqt, _Float16* __restrict__ mu_out) {
    __shared__ char lds[61440];
    unsigned short* Xs = (unsigned short*)(lds);                 // [64][136] bf16
    unsigned short* Zs = (unsigned short*)(lds + 17408);         // [64][272] bf16
    unsigned short* Qs = (unsigned short*)(lds + 17408 + 34816); // [64][72]  bf16

    const int tid = threadIdx.x;
    const int lane = tid & 63;
    const int w = tid >> 6;
    const int q4 = lane >> 4;
    const int l16 = lane & 15;
    const int rowbase = blockIdx.x * 64;

    // stage X = [A|B] as bf16 (vector float2 loads, packed uint writes)
    uint32* Xu = (uint32*)Xs; // row stride 68 uints
    for (int i = tid; i < 64 * 64; i += 256) {
        int r = i >> 6, j2 = i & 63;
        const float* src = (j2 < 32) ? (A + (size_t)(rowbase + r) * 64 + 2 * j2)
                                     : (B + (size_t)(rowbase + r) * 64 + 2 * (j2 - 32));
        float2 v = *(const float2*)src;
        Xu[r * 68 + j2] = (uint32)f2bf(v.x) | ((uint32)f2bf(v.y) << 16);
    }
    // stage Q
    uint32* Qu = (uint32*)Qs; // row stride 36 uints
    for (int i = tid; i < 64 * 32; i += 256) {
        int r = i >> 5, j2 = i & 31;
        float2 v = *(const float2*)(Q + (size_t)(rowbase + r) * 64 + 2 * j2);
        Qu[r * 36 + j2] = (uint32)f2bf(v.x) | ((uint32)f2bf(v.y) << 16);
    }
    __syncthreads();

    // preload A-frags for all 4 m-tiles x 4 k-tiles
    short8 ax[4][4];
#pragma unroll
    for (int m = 0; m < 4; m++)
#pragma unroll
        for (int kt = 0; kt < 4; kt++)
            ax[m][kt] = *(const short8*)&Xs[(m * 16 + l16) * 136 + kt * 32 + q4 * 8];

    // GEMM1: Z = relu(X @ W1 + b1), wave computes col stripe [w*64, w*64+64)
#pragma unroll
    for (int nt = 0; nt < 4; nt++) {
        const int ng = w * 4 + nt;
        short8 wf[4];
#pragma unroll
        for (int kt = 0; kt < 4; kt++)
            wf[kt] = *(const short8*)&w1t[(ng * 16 + l16) * 128 + kt * 32 + q4 * 8];
        floatx4 acc[4];
#pragma unroll
        for (int m = 0; m < 4; m++) acc[m] = (floatx4){0.f, 0.f, 0.f, 0.f};
#pragma unroll
        for (int kt = 0; kt < 4; kt++)
#pragma unroll
            for (int m = 0; m < 4; m++)
                acc[m] = __builtin_amdgcn_mfma_f32_16x16x32_bf16(ax[m][kt], wf[kt], acc[m], 0, 0, 0);
        const int col = ng * 16 + l16;
        const float b1v = b1[col];
#pragma unroll
        for (int m = 0; m < 4; m++)
#pragma unroll
            for (int r = 0; r < 4; r++) {
                float z = acc[m][r] + b1v;
                z = z > 0.f ? z : 0.f;
                Zs[(m * 16 + q4 * 4 + r) * 272 + col] = f2bf(z);
            }
    }
    // preload GEMM2/GEMM3 B-frags (registers, from L2-hot workspace)
    short8 w2f[8], wqf[2];
#pragma unroll
    for (int kt = 0; kt < 8; kt++)
        w2f[kt] = *(const short8*)&w2t[(w * 16 + l16) * 256 + kt * 32 + q4 * 8];
#pragma unroll
    for (int kt = 0; kt < 2; kt++)
        wqf[kt] = *(const short8*)&wqt[(w * 16 + l16) * 64 + kt * 32 + q4 * 8];
    __syncthreads();

    // GEMM2: mu_pre = Z @ W2 ; GEMM3: gate_pre = q @ Wq  (wave owns out cols w*16..w*16+15)
    floatx4 acc2[4], acc3[4];
#pragma unroll
    for (int m = 0; m < 4; m++) { acc2[m] = (floatx4){0.f,0.f,0.f,0.f}; acc3[m] = (floatx4){0.f,0.f,0.f,0.f}; }
#pragma unroll
    for (int m = 0; m < 4; m++)
#pragma unroll
        for (int kt = 0; kt < 8; kt++) {
            short8 az = *(const short8*)&Zs[(m * 16 + l16) * 272 + kt * 32 + q4 * 8];
            acc2[m] = __builtin_amdgcn_mfma_f32_16x16x32_bf16(az, w2f[kt], acc2[m], 0, 0, 0);
        }
#pragma unroll
    for (int m = 0; m < 4; m++)
#pragma unroll
        for (int kt = 0; kt < 2; kt++) {
            short8 aq = *(const short8*)&Qs[(m * 16 + l16) * 72 + kt * 32 + q4 * 8];
            acc3[m] = __builtin_amdgcn_mfma_f32_16x16x32_bf16(aq, wqf[kt], acc3[m], 0, 0, 0);
        }
    // epilogue
    const int col = w * 16 + l16;
    const float b2v = b2[col], bqv = bq[col];
#pragma unroll
    for (int m = 0; m < 4; m++)
#pragma unroll
        for (int r = 0; r < 4; r++) {
            int row = m * 16 + q4 * 4 + r;
            float sp = fast_softplus(acc2[m][r] + b2v);
            float g = fast_tanh(acc3[m][r] + bqv);
            float mu = sp * (1.f + 0.5f * g);
            mu_out[(size_t)(rowbase + row) * 64 + col] = (_Float16)mu;
        }
}

// ---------------- K=6 iterations + energy, register-resident chains ----------------
// Thread (col=tid&63, g=tid>>6) owns 19 CONTIGUOUS rows of the 76-row window (halo 6).
// Only cross-thread traffic: 4 boundary values/thread/iter via 8KB double-buffered LDS
// exchange -> 1 barrier per iteration.
__global__ __launch_bounds__(256) void iter_kernel(
    const float* __restrict__ A, const float* __restrict__ B, const _Float16* __restrict__ mu_ws,
    float* __restrict__ outA, float* __restrict__ outB, float* __restrict__ energy) {
    __shared__ float ex[2][4][4][64]; // [parity][val: tA_top,tA_bot,tB_top,tB_bot][g][col]
    __shared__ float esm[4];
    const int tid = threadIdx.x;
    const int col = tid & 63;
    const int g = tid >> 6;
    const int b = blockIdx.y;
    const int s = blockIdx.x * 64;
    const size_t bbase = (size_t)b * 8192;
    const int r0 = g * 19;

    float a[19], bv[19], me[19];
#pragma unroll
    for (int i = 0; i < 19; i++) {
        int gl = (s + r0 + i + 8192 - 6) & 8191; // circular
        size_t idx = (bbase + gl) * 64 + col;
        a[i] = A[idx];
        bv[i] = B[idx];
        me[i] = ETA * (float)mu_ws[idx];
    }
    for (int it = 0; it < 6; it++) {
        float st[19];
#pragma unroll
        for (int i = 0; i < 19; i++) st[i] = me[i] * (a[i] - bv[i]);
        float* exb = &ex[it & 1][0][0][0];
        exb[0 * 256 + g * 64 + col] = a[0] - st[0];
        exb[1 * 256 + g * 64 + col] = a[18] - st[18];
        exb[2 * 256 + g * 64 + col] = bv[0] + st[0];
        exb[3 * 256 + g * 64 + col] = bv[18] + st[18];
        __syncthreads();
        // outer-boundary clamp values are garbage-tolerant (validity erodes 1 row/iter, halo=6)
        float tAup = (g > 0) ? exb[1 * 256 + (g - 1) * 64 + col] : a[0] - st[0];
        float tAdn = (g < 3) ? exb[0 * 256 + (g + 1) * 64 + col] : a[18] - st[18];
        float tBup = (g > 0) ? exb[3 * 256 + (g - 1) * 64 + col] : bv[0] + st[0];
        float tBdn = (g < 3) ? exb[2 * 256 + (g + 1) * 64 + col] : bv[18] + st[18];
        // A pass (rolling 3-point window over tA = a - st)
        float prev = tAup, cur = a[0] - st[0];
#pragma unroll
        for (int i = 0; i < 19; i++) {
            float nxt = (i < 18) ? (a[i + 1] - st[i + 1]) : tAdn;
            a[i] = cur - LAM * (2.f * cur - prev - nxt);
            prev = cur; cur = nxt;
        }
        // B pass (tB = b + st)
        prev = tBup; cur = bv[0] + st[0];
#pragma unroll
        for (int i = 0; i < 19; i++) {
            float nxt = (i < 18) ? (bv[i + 1] + st[i + 1]) : tBdn;
            bv[i] = cur - LAM * (2.f * cur - prev - nxt);
            prev = cur; cur = nxt;
        }
    }
    // store interior rows + energy partial
    float e = 0.f;
#pragma unroll
    for (int i = 0; i < 19; i++) {
        int r = r0 + i;
        if (r >= 6 && r < 70) {
            float d = a[i] - bv[i];
            e += me[i] * d * d;
            size_t gidx = (bbase + s + (r - 6)) * 64 + col;
            outA[gidx] = a[i];
            outB[gidx] = bv[i];
        }
    }
    e *= 0.5f / ETA;
#pragma unroll
    for (int off = 32; off > 0; off >>= 1) e += __shfl_down(e, off, 64);
    if ((tid & 63) == 0) esm[g] = e;
    __syncthreads();
    if (tid == 0) atomicAdd(energy + b, esm[0] + esm[1] + esm[2] + esm[3]);
}

extern "C" void kernel_launch(void* const* d_in, const int* in_sizes, int n_in,
                              void* d_out, int out_size, void* d_ws, size_t ws_size,
                              hipStream_t stream) {
    const float* A  = (const float*)d_in[0];
    const float* B  = (const float*)d_in[1];
    const float* Q  = (const float*)d_in[2];
    const float* W1 = (const float*)d_in[3];
    const float* b1 = (const float*)d_in[4];
    const float* W2 = (const float*)d_in[5];
    const float* b2 = (const float*)d_in[6];
    const float* Wq = (const float*)d_in[7];
    const float* bq = (const float*)d_in[8];

    float* outA = (float*)d_out;
    float* outB = outA + (size_t)RTOT * 64;
    float* energy = outB + (size_t)RTOT * 64;

    char* ws = (char*)d_ws;
    _Float16* mu_ws = (_Float16*)ws;
    unsigned short* w1t = (unsigned short*)(ws + W1T_OFF);
    unsigned short* w2t = (unsigned short*)(ws + W2T_OFF);
    unsigned short* wqt = (unsigned short*)(ws + WQT_OFF);

    hipLaunchKernelGGL(prep_kernel, dim3(64), dim3(256), 0, stream,
                       W1, W2, Wq, w1t, w2t, wqt, energy);
    hipLaunchKernelGGL(mlp_kernel, dim3(RTOT / 64), dim3(256), 0, stream,
                       A, B, Q, b1, b2, bq, w1t, w2t, wqt, mu_ws);
    hipLaunchKernelGGL(iter_kernel, dim3(LL / 64, BSZ), dim3(256), 0, stream,
                       A, B, mu_ws, outA, outB, energy);
}

// Round 3
// 409.770 us; speedup vs baseline: 1.3983x; 1.0105x over previous
//
#include <hip/hip_runtime.h>
#include <hip/hip_bf16.h>
#include <hip/hip_fp16.h>

#define ETA 0.15f
#define LAM 0.05f

typedef unsigned int uint32;
typedef __attribute__((ext_vector_type(8))) short short8;
typedef __attribute__((ext_vector_type(4))) float floatx4;
typedef __attribute__((ext_vector_type(4))) _Float16 half4;

static const int BSZ = 32, LL = 8192, DD = 64;
static const int RTOT = BSZ * LL; // 262144 rows

// workspace layout (bytes)
static const size_t MU_BYTES = (size_t)RTOT * DD * 2;   // mu as fp16
static const size_t W1T_OFF  = MU_BYTES;                // [256][128] bf16 (n-major)
static const size_t W2T_OFF  = W1T_OFF + 256 * 128 * 2; // [64][256] bf16
static const size_t WQT_OFF  = W2T_OFF + 64 * 256 * 2;  // [64][64] bf16

__device__ __forceinline__ unsigned short f2bf(float f) {
    uint32 u = __builtin_bit_cast(uint32, f);
    uint32 r = (u + 0x7FFFu + ((u >> 16) & 1u)) >> 16;
    return (unsigned short)r;
}
__device__ __forceinline__ float fast_softplus(float x) {
    return fmaxf(x, 0.f) + __logf(1.f + __expf(-fabsf(x)));
}
__device__ __forceinline__ float fast_tanh(float x) {
    float t = __expf(-2.f * fabsf(x));
    float r = (1.f - t) / (1.f + t);
    return copysignf(r, x);
}

// ---------------- prep: zero energy, transpose weights to bf16 ----------------
__global__ void prep_kernel(const float* __restrict__ W1, const float* __restrict__ W2,
                            const float* __restrict__ Wq,
                            unsigned short* __restrict__ w1t, unsigned short* __restrict__ w2t,
                            unsigned short* __restrict__ wqt, float* __restrict__ energy) {
    int tid = blockIdx.x * blockDim.x + threadIdx.x;
    int nth = gridDim.x * blockDim.x;
    for (int i = tid; i < 256 * 128; i += nth) { int n = i >> 7, k = i & 127; w1t[i] = f2bf(W1[k * 256 + n]); }
    for (int i = tid; i < 64 * 256; i += nth) { int n = i >> 8, k = i & 255; w2t[i] = f2bf(W2[k * 64 + n]); }
    for (int i = tid; i < 64 * 64;  i += nth) { int n = i >> 6, k = i & 63;  wqt[i] = f2bf(Wq[k * 64 + n]); }
    if (tid < 32) energy[tid] = 0.f;
}

// ---------------- MLP ----------------
// 64 rows/block, 4 waves. GEMM3 first (frees Qs), X-frags preloaded to regs (frees Xs),
// then Zs overlays the staging region: LDS = 34816 B -> 4 blocks/CU.
__global__ __launch_bounds__(256) void mlp_kernel(
    const float* __restrict__ A, const float* __restrict__ B, const float* __restrict__ Q,
    const float* __restrict__ b1, const float* __restrict__ b2, const float* __restrict__ bq,
    const unsigned short* __restrict__ w1t, const unsigned short* __restrict__ w2t,
    const unsigned short* __restrict__ wqt, _Float16* __restrict__ mu_out) {
    __shared__ char lds[34816];
    unsigned short* Xs = (unsigned short*)(lds);          // [64][136] bf16 (staging phase)
    unsigned short* Qs = (unsigned short*)(lds + 17408);  // [64][72]  bf16 (staging phase)
    unsigned short* Zs = (unsigned short*)(lds);          // [64][272] bf16 (overlays after barrier 2)

    const int tid = threadIdx.x;
    const int lane = tid & 63;
    const int w = tid >> 6;
    const int q4 = lane >> 4;
    const int l16 = lane & 15;
    const int rowbase = blockIdx.x * 64;

    // stage X = [A|B] as bf16
    uint32* Xu = (uint32*)Xs; // row stride 68 uints
    for (int i = tid; i < 64 * 64; i += 256) {
        int r = i >> 6, j2 = i & 63;
        const float* src = (j2 < 32) ? (A + (size_t)(rowbase + r) * 64 + 2 * j2)
                                     : (B + (size_t)(rowbase + r) * 64 + 2 * (j2 - 32));
        float2 v = *(const float2*)src;
        Xu[r * 68 + j2] = (uint32)f2bf(v.x) | ((uint32)f2bf(v.y) << 16);
    }
    // stage Q
    uint32* Qu = (uint32*)Qs; // row stride 36 uints
    for (int i = tid; i < 64 * 32; i += 256) {
        int r = i >> 5, j2 = i & 31;
        float2 v = *(const float2*)(Q + (size_t)(rowbase + r) * 64 + 2 * j2);
        Qu[r * 36 + j2] = (uint32)f2bf(v.x) | ((uint32)f2bf(v.y) << 16);
    }
    __syncthreads();

    // GEMM3: gate_pre = q @ Wq (wave owns out cols w*16..w*16+15); result held in regs
    floatx4 acc3[4];
#pragma unroll
    for (int m = 0; m < 4; m++) acc3[m] = (floatx4){0.f, 0.f, 0.f, 0.f};
    {
        short8 wqf[2];
#pragma unroll
        for (int kt = 0; kt < 2; kt++)
            wqf[kt] = *(const short8*)&wqt[(w * 16 + l16) * 64 + kt * 32 + q4 * 8];
#pragma unroll
        for (int m = 0; m < 4; m++)
#pragma unroll
            for (int kt = 0; kt < 2; kt++) {
                short8 aq = *(const short8*)&Qs[(m * 16 + l16) * 72 + kt * 32 + q4 * 8];
                acc3[m] = __builtin_amdgcn_mfma_f32_16x16x32_bf16(aq, wqf[kt], acc3[m], 0, 0, 0);
            }
    }
    // preload X fragments (4 m-tiles x 4 k-tiles) so Xs region can be reused
    short8 ax[4][4];
#pragma unroll
    for (int m = 0; m < 4; m++)
#pragma unroll
        for (int kt = 0; kt < 4; kt++)
            ax[m][kt] = *(const short8*)&Xs[(m * 16 + l16) * 136 + kt * 32 + q4 * 8];
    __syncthreads(); // all reads of Xs/Qs done; Zs may now overlay

    // GEMM1: Z = relu(X @ W1 + b1), wave computes col stripe [w*64, w*64+64)
#pragma unroll
    for (int nt = 0; nt < 4; nt++) {
        const int ng = w * 4 + nt;
        short8 wf[4];
#pragma unroll
        for (int kt = 0; kt < 4; kt++)
            wf[kt] = *(const short8*)&w1t[(ng * 16 + l16) * 128 + kt * 32 + q4 * 8];
        floatx4 acc[4];
#pragma unroll
        for (int m = 0; m < 4; m++) acc[m] = (floatx4){0.f, 0.f, 0.f, 0.f};
#pragma unroll
        for (int kt = 0; kt < 4; kt++)
#pragma unroll
            for (int m = 0; m < 4; m++)
                acc[m] = __builtin_amdgcn_mfma_f32_16x16x32_bf16(ax[m][kt], wf[kt], acc[m], 0, 0, 0);
        const int col = ng * 16 + l16;
        const float b1v = b1[col];
#pragma unroll
        for (int m = 0; m < 4; m++)
#pragma unroll
            for (int r = 0; r < 4; r++) {
                float z = acc[m][r] + b1v;
                z = z > 0.f ? z : 0.f;
                Zs[(m * 16 + q4 * 4 + r) * 272 + col] = f2bf(z);
            }
    }
    // preload GEMM2 B-frags while waiting on barrier
    short8 w2f[8];
#pragma unroll
    for (int kt = 0; kt < 8; kt++)
        w2f[kt] = *(const short8*)&w2t[(w * 16 + l16) * 256 + kt * 32 + q4 * 8];
    __syncthreads();

    // GEMM2: mu_pre = Z @ W2 (wave owns out cols w*16..w*16+15)
    floatx4 acc2[4];
#pragma unroll
    for (int m = 0; m < 4; m++) acc2[m] = (floatx4){0.f, 0.f, 0.f, 0.f};
#pragma unroll
    for (int m = 0; m < 4; m++)
#pragma unroll
        for (int kt = 0; kt < 8; kt++) {
            short8 az = *(const short8*)&Zs[(m * 16 + l16) * 272 + kt * 32 + q4 * 8];
            acc2[m] = __builtin_amdgcn_mfma_f32_16x16x32_bf16(az, w2f[kt], acc2[m], 0, 0, 0);
        }
    // epilogue
    const int col = w * 16 + l16;
    const float b2v = b2[col], bqv = bq[col];
#pragma unroll
    for (int m = 0; m < 4; m++)
#pragma unroll
        for (int r = 0; r < 4; r++) {
            int row = m * 16 + q4 * 4 + r;
            float sp = fast_softplus(acc2[m][r] + b2v);
            float g = fast_tanh(acc3[m][r] + bqv);
            float mu = sp * (1.f + 0.5f * g);
            mu_out[(size_t)(rowbase + row) * 64 + col] = (_Float16)mu;
        }
}

// ---------------- K=6 iterations + energy ----------------
// Thread (c4=tid&15, g=tid>>4) owns cols c4*4..+3 of rows g*5..g*5+4 in an 80-row
// window (halo 8 each side; validity erodes 1 row/iter, 6 < 8). float4 chains in
// registers; 1 barrier/iter via 32KB double-buffered boundary exchange.
__global__ __launch_bounds__(256) void iter_kernel(
    const float* __restrict__ A, const float* __restrict__ B, const _Float16* __restrict__ mu_ws,
    float* __restrict__ outA, float* __restrict__ outB, float* __restrict__ energy) {
    __shared__ float ex[2][4][16][64]; // [parity][aTop,aBot,bTop,bBot][g][col]
    __shared__ float esm[4];
    const int tid = threadIdx.x;
    const int c4 = tid & 15;
    const int g = tid >> 4;
    const int b = blockIdx.y;
    const int s = blockIdx.x * 64;
    const size_t bbase = (size_t)b * 8192;
    const int r0 = g * 5;

    floatx4 a[5], bv[5], me[5];
#pragma unroll
    for (int i = 0; i < 5; i++) {
        int gl = (s + r0 + i + 8192 - 8) & 8191; // window starts at s-8 (circular)
        size_t base = (bbase + gl) * 64 + c4 * 4;
        a[i] = *(const floatx4*)(A + base);
        bv[i] = *(const floatx4*)(B + base);
        half4 m4 = *(const half4*)(mu_ws + base);
        me[i] = __builtin_convertvector(m4, floatx4) * ETA;
    }
    for (int it = 0; it < 6; it++) {
        // step in place: a <- a - st, b <- b + st
#pragma unroll
        for (int i = 0; i < 5; i++) {
            floatx4 st = me[i] * (a[i] - bv[i]);
            a[i] = a[i] - st;
            bv[i] = bv[i] + st;
        }
        const int p = it & 1;
        *(floatx4*)&ex[p][0][g][c4 * 4] = a[0];
        *(floatx4*)&ex[p][1][g][c4 * 4] = a[4];
        *(floatx4*)&ex[p][2][g][c4 * 4] = bv[0];
        *(floatx4*)&ex[p][3][g][c4 * 4] = bv[4];
        __syncthreads();
        floatx4 aUp = (g > 0)  ? *(const floatx4*)&ex[p][1][g - 1][c4 * 4] : a[0];
        floatx4 aDn = (g < 15) ? *(const floatx4*)&ex[p][0][g + 1][c4 * 4] : a[4];
        floatx4 bUp = (g > 0)  ? *(const floatx4*)&ex[p][3][g - 1][c4 * 4] : bv[0];
        floatx4 bDn = (g < 15) ? *(const floatx4*)&ex[p][2][g + 1][c4 * 4] : bv[4];
        // smooth A (rolling 3-point)
        floatx4 prev = aUp, cur = a[0];
#pragma unroll
        for (int i = 0; i < 5; i++) {
            floatx4 nxt = (i < 4) ? a[i + 1] : aDn;
            a[i] = cur - LAM * (2.f * cur - prev - nxt);
            prev = cur; cur = nxt;
        }
        // smooth B
        prev = bUp; cur = bv[0];
#pragma unroll
        for (int i = 0; i < 5; i++) {
            floatx4 nxt = (i < 4) ? bv[i + 1] : bDn;
            bv[i] = cur - LAM * (2.f * cur - prev - nxt);
            prev = cur; cur = nxt;
        }
    }
    // store interior rows (window rows 8..71) + energy partial
    float e = 0.f;
#pragma unroll
    for (int i = 0; i < 5; i++) {
        int wr = r0 + i;
        if (wr >= 8 && wr < 72) {
            floatx4 d = a[i] - bv[i];
            floatx4 q = me[i] * d * d;
            e += q.x + q.y + q.z + q.w;
            size_t gidx = (bbase + s + (wr - 8)) * 64 + c4 * 4;
            *(floatx4*)(outA + gidx) = a[i];
            *(floatx4*)(outB + gidx) = bv[i];
        }
    }
    e *= 0.5f / ETA;
#pragma unroll
    for (int off = 32; off > 0; off >>= 1) e += __shfl_down(e, off, 64);
    if ((tid & 63) == 0) esm[tid >> 6] = e;
    __syncthreads();
    if (tid == 0) atomicAdd(energy + b, esm[0] + esm[1] + esm[2] + esm[3]);
}

extern "C" void kernel_launch(void* const* d_in, const int* in_sizes, int n_in,
                              void* d_out, int out_size, void* d_ws, size_t ws_size,
                              hipStream_t stream) {
    const float* A  = (const float*)d_in[0];
    const float* B  = (const float*)d_in[1];
    const float* Q  = (const float*)d_in[2];
    const float* W1 = (const float*)d_in[3];
    const float* b1 = (const float*)d_in[4];
    const float* W2 = (const float*)d_in[5];
    const float* b2 = (const float*)d_in[6];
    const float* Wq = (const float*)d_in[7];
    const float* bq = (const float*)d_in[8];

    float* outA = (float*)d_out;
    float* outB = outA + (size_t)RTOT * 64;
    float* energy = outB + (size_t)RTOT * 64;

    char* ws = (char*)d_ws;
    _Float16* mu_ws = (_Float16*)ws;
    unsigned short* w1t = (unsigned short*)(ws + W1T_OFF);
    unsigned short* w2t = (unsigned short*)(ws + W2T_OFF);
    unsigned short* wqt = (unsigned short*)(ws + WQT_OFF);

    hipLaunchKernelGGL(prep_kernel, dim3(64), dim3(256), 0, stream,
                       W1, W2, Wq, w1t, w2t, wqt, energy);
    hipLaunchKernelGGL(mlp_kernel, dim3(RTOT / 64), dim3(256), 0, stream,
                       A, B, Q, b1, b2, bq, w1t, w2t, wqt, mu_ws);
    hipLaunchKernelGGL(iter_kernel, dim3(LL / 64, BSZ), dim3(256), 0, stream,
                       A, B, mu_ws, outA, outB, energy);
}